// Round 3
// baseline (467.596 us; speedup 1.0000x reference)
//
#include <hip/hip_runtime.h>
#include <hip/hip_fp16.h>

#define NG 64              // graphs (= Y feature width)
#define NGRAPH_C 64

// edge multi-split geometry
#define RSZ 12500          // nodes per range (8 ranges for n=100000)
#define RSZP 6250          // packed u16 pairs per range
#define NC_MS 64           // edge chunks

// word counting-sort geometry
#define VOC 10000
#define VOCP 5000          // packed u16 pairs
#define NC_W 128           // node chunks for word sort
#define WB 40              // words per fused block
#define NWB 250            // fused blocks (WB*NWB = VOC)

// ---- bit casts ----
__device__ __forceinline__ unsigned f_as_u(float f) { union { float f; unsigned u; } c; c.f = f; return c.u; }
__device__ __forceinline__ float u_as_f(unsigned u) { union { unsigned u; float f; } c; c.u = u; return c.f; }

// XCD id (0..7)
__device__ __forceinline__ int xcc_id() {
    unsigned x;
    asm volatile("s_getreg_b32 %0, hwreg(HW_REG_XCC_ID)" : "=s"(x));
    return (int)(x & 7u);
}

union H4 { uint2 u2; __half h[4]; };

// ---------------- edge multi-split count ----------------
__global__ __launch_bounds__(256) void k_mscount(const int* __restrict__ src, const int* __restrict__ dst,
                                                 unsigned* __restrict__ rep_in,
                                                 unsigned* __restrict__ rep_src,
                                                 int e, int n, int chunk, int npairs) {
    __shared__ unsigned hin[RSZP];
    __shared__ unsigned hsrc[RSZP];
    int c = blockIdx.x % NC_MS;
    int r = blockIdx.x / NC_MS;
    int base = r * RSZ;
    int t = threadIdx.x;
    for (int w = t; w < RSZP; w += 256) { hin[w] = 0u; hsrc[w] = 0u; }
    __syncthreads();
    int e0 = c * chunk, e1 = min(e, e0 + chunk);
    for (int i = e0 + t; i < e1; i += 256) {
        int s = src[i], d = dst[i];
        unsigned ud = (unsigned)(d - base);
        unsigned us = (unsigned)(s - base);
        if (ud < (unsigned)RSZ) atomicAdd(&hin[ud >> 1], 1u << ((ud & 1) * 16));
        if (us < (unsigned)RSZ) atomicAdd(&hsrc[us >> 1], 1u << ((us & 1) * 16));
    }
    __syncthreads();
    int lim = min(RSZ, n - base);
    if (lim <= 0) return;
    int plim = (lim + 1) >> 1;
    unsigned* gin  = rep_in  + (size_t)c * npairs + (base >> 1);
    unsigned* gsrc = rep_src + (size_t)c * npairs + (base >> 1);
    for (int w = t; w < plim; w += 256) { gin[w] = hin[w]; gsrc[w] = hsrc[w]; }
}

__global__ __launch_bounds__(256) void k_msreduce(const unsigned* __restrict__ rep_in,
                                                  unsigned* __restrict__ rep_src,   // -> pref
                                                  float* __restrict__ dinv,
                                                  unsigned* __restrict__ counts_src,
                                                  int n, int npairs) {
    int i2 = blockIdx.x * 256 + threadIdx.x;
    if (i2 >= npairs) return;
    unsigned slo = 0, shi = 0, rlo = 0, rhi = 0;
#pragma unroll 4
    for (int c = 0; c < NC_MS; ++c) {
        unsigned vi = rep_in[(size_t)c * npairs + i2];
        slo += vi & 0xFFFFu; shi += vi >> 16;
        unsigned vs = rep_src[(size_t)c * npairs + i2];
        rep_src[(size_t)c * npairs + i2] = rlo | (rhi << 16);
        rlo += vs & 0xFFFFu; rhi += vs >> 16;
    }
    int i = i2 * 2;
    dinv[i] = rsqrtf((float)(slo + 1u));
    counts_src[i] = rlo;
    if (i + 1 < n) {
        dinv[i + 1] = rsqrtf((float)(shi + 1u));
        counts_src[i + 1] = rhi;
    }
}

// ---------------- 2-level exclusive scan ----------------
__global__ __launch_bounds__(256) void k_blocksum(const unsigned* __restrict__ counts,
                                                  unsigned* __restrict__ partials, int n) {
    __shared__ unsigned s[256];
    int base = blockIdx.x * 1024;
    unsigned sum = 0;
    for (int j = threadIdx.x; j < 1024; j += 256) {
        int i = base + j;
        sum += (i < n) ? counts[i] : 0u;
    }
    s[threadIdx.x] = sum;
    __syncthreads();
    for (int off = 128; off > 0; off >>= 1) {
        if (threadIdx.x < (unsigned)off) s[threadIdx.x] += s[threadIdx.x + off];
        __syncthreads();
    }
    if (threadIdx.x == 0) partials[blockIdx.x] = s[0];
}

__global__ __launch_bounds__(128) void k_scanpartials(unsigned* __restrict__ partials, int nb) {
    __shared__ unsigned s[128];
    int t = threadIdx.x;
    s[t] = (t < nb) ? partials[t] : 0u;
    __syncthreads();
    if (t == 0) {
        unsigned run = 0;
        for (int i = 0; i < nb; ++i) { unsigned v = s[i]; s[i] = run; run += v; }
    }
    __syncthreads();
    if (t < nb) partials[t] = s[t];
}

__global__ __launch_bounds__(256) void k_scanblock(const unsigned* __restrict__ counts,
                                                   const unsigned* __restrict__ partials,
                                                   unsigned* __restrict__ row_start, int n) {
    __shared__ unsigned s[256];
    int base = blockIdx.x * 1024;
    int t = threadIdx.x;
    unsigned v[4];
    unsigned tsum = 0;
#pragma unroll
    for (int j = 0; j < 4; ++j) {
        int i = base + t * 4 + j;
        v[j] = (i < n) ? counts[i] : 0u;
        tsum += v[j];
    }
    s[t] = tsum;
    __syncthreads();
    for (int off = 1; off < 256; off <<= 1) {
        unsigned x = (t >= off) ? s[t - off] : 0u;
        __syncthreads();
        s[t] += x;
        __syncthreads();
    }
    unsigned excl = (t > 0 ? s[t - 1] : 0u) + partials[blockIdx.x];
#pragma unroll
    for (int j = 0; j < 4; ++j) {
        int i = base + t * 4 + j;
        if (i < n) {
            row_start[i] = excl;
            excl += v[j];
            if (i == n - 1) row_start[n] = excl;
        }
    }
}

// ---------------- edge multi-split fill ----------------
__global__ __launch_bounds__(256) void k_msfill(const int* __restrict__ src, const int* __restrict__ dst,
                                                const int* __restrict__ batch,
                                                const unsigned* __restrict__ row_start,
                                                const unsigned* __restrict__ pref,
                                                const float* __restrict__ dinv,
                                                uint2* __restrict__ euv,
                                                int e, int n, int chunk, int npairs) {
    __shared__ unsigned cur[RSZP];
    int c = blockIdx.x % NC_MS;
    int r = blockIdx.x / NC_MS;
    int base = r * RSZ;
    int t = threadIdx.x;
    for (int w = t; w < RSZP; w += 256) cur[w] = 0u;
    __syncthreads();
    int e0 = c * chunk, e1 = min(e, e0 + chunk);
    const unsigned* prefc = pref + (size_t)c * npairs;
    for (int i = e0 + t; i < e1; i += 256) {
        int s = src[i];
        unsigned us = (unsigned)(s - base);
        if (us < (unsigned)RSZ) {
            int d = dst[i];
            unsigned sh = (us & 1) * 16;
            unsigned old = atomicAdd(&cur[us >> 1], 1u << sh);
            unsigned slot = (old >> sh) & 0xFFFFu;
            unsigned p16 = (prefc[(unsigned)s >> 1] >> ((s & 1) * 16)) & 0xFFFFu;
            unsigned pos = row_start[s] + p16 + slot;
            uint2 pv;
            pv.x = (unsigned)d | ((unsigned)batch[d] << 17);
            pv.y = f_as_u(dinv[s] * dinv[d]);
            euv[pos] = pv;
        }
    }
}

// ---------------- word counting sort: count / reduce / fill ----------------
__global__ __launch_bounds__(256) void k_wmscount(const int* __restrict__ x,
                                                  unsigned* __restrict__ rep_w,
                                                  int n, int chunk) {
    __shared__ unsigned h[VOCP];
    int c = blockIdx.x;
    int t = threadIdx.x;
    for (int w = t; w < VOCP; w += 256) h[w] = 0u;
    __syncthreads();
    int j0 = c * chunk, j1 = min(n, j0 + chunk);
    for (int j = j0 + t; j < j1; j += 256) {
        int w = x[2 * j + 1];
        atomicAdd(&h[w >> 1], 1u << ((w & 1) * 16));
    }
    __syncthreads();
    unsigned* g = rep_w + (size_t)c * VOCP;
    for (int w = t; w < VOCP; w += 256) g[w] = h[w];
}

__global__ __launch_bounds__(256) void k_wmsreduce(unsigned* __restrict__ rep_w,   // -> pref
                                                   unsigned* __restrict__ counts_w) {
    int i2 = blockIdx.x * 256 + threadIdx.x;
    if (i2 >= VOCP) return;
    unsigned rlo = 0, rhi = 0;
#pragma unroll 4
    for (int c = 0; c < NC_W; ++c) {
        unsigned v = rep_w[(size_t)c * VOCP + i2];
        rep_w[(size_t)c * VOCP + i2] = rlo | (rhi << 16);
        rlo += v & 0xFFFFu; rhi += v >> 16;
    }
    counts_w[2 * i2] = rlo;
    counts_w[2 * i2 + 1] = rhi;
}

__global__ __launch_bounds__(256) void k_wmsfill(const int* __restrict__ x,
                                                 const unsigned* __restrict__ wstart,
                                                 const unsigned* __restrict__ pref,
                                                 unsigned* __restrict__ sorted,
                                                 int n, int chunk) {
    __shared__ unsigned cur[VOCP];
    int c = blockIdx.x;
    int t = threadIdx.x;
    for (int w = t; w < VOCP; w += 256) cur[w] = 0u;
    __syncthreads();
    int j0 = c * chunk, j1 = min(n, j0 + chunk);
    const unsigned* prefc = pref + (size_t)c * VOCP;
    for (int j = j0 + t; j < j1; j += 256) {
        int w = x[2 * j + 1];
        unsigned sh = (w & 1) * 16;
        unsigned old = atomicAdd(&cur[w >> 1], 1u << sh);
        unsigned slot = (old >> sh) & 0xFFFFu;
        unsigned p16 = (prefc[w >> 1] >> sh) & 0xFFFFu;
        sorted[wstart[w] + p16 + slot] = (unsigned)j;
    }
}

// ---------------- graph boundaries (batch sorted) ----------------
__global__ __launch_bounds__(128) void k_gstart(const int* __restrict__ batch,
                                                int* __restrict__ gstart, int n, int ngraph) {
    int g = threadIdx.x;
    if (g > ngraph) return;
    if (g == ngraph) { gstart[g] = n; return; }
    int lo = 0, hi = n;
    while (lo < hi) {
        int mid = (lo + hi) >> 1;
        if (batch[mid] < g) lo = mid + 1; else hi = mid;
    }
    gstart[g] = lo;
}

// ---------------- hop 1 (fp16 out) ----------------
__global__ __launch_bounds__(256) void k_y1(const int* __restrict__ batch,
                                            const float* __restrict__ dinv,
                                            const unsigned* __restrict__ row_start,
                                            const uint2* __restrict__ euv,
                                            __half* __restrict__ Y1, int n) {
    int idx = blockIdx.x * 256 + threadIdx.x;
    if (idx >= n * 16) return;
    int j = idx >> 4;
    int c4 = idx & 15;
    int cb = c4 * 4;
    float a0 = 0.f, a1 = 0.f, a2 = 0.f, a3 = 0.f;
    {
        int bj = batch[j];
        float dj = dinv[j];
        float sn = dj * dj;
        a0 += (bj == cb + 0) ? sn : 0.f;
        a1 += (bj == cb + 1) ? sn : 0.f;
        a2 += (bj == cb + 2) ? sn : 0.f;
        a3 += (bj == cb + 3) ? sn : 0.f;
    }
    unsigned e0 = row_start[j], e1 = row_start[j + 1];
    for (unsigned e = e0; e < e1; ++e) {
        uint2 p = euv[e];
        int bd = (int)(p.x >> 17);
        float v = u_as_f(p.y);
        a0 += (bd == cb + 0) ? v : 0.f;
        a1 += (bd == cb + 1) ? v : 0.f;
        a2 += (bd == cb + 2) ? v : 0.f;
        a3 += (bd == cb + 3) ? v : 0.f;
    }
    H4 o;
    o.h[0] = __float2half(a0); o.h[1] = __float2half(a1);
    o.h[2] = __float2half(a2); o.h[3] = __float2half(a3);
    *(uint2*)&Y1[(size_t)j * NG + cb] = o.u2;
}

// ---------------- Y-hop fp16 -> fp16 ----------------
__global__ __launch_bounds__(256) void k_yprop(const __half* __restrict__ Yin,
                                               const float* __restrict__ dinv,
                                               const unsigned* __restrict__ row_start,
                                               const uint2* __restrict__ euv,
                                               __half* __restrict__ Yout, int n) {
    int idx = blockIdx.x * 256 + threadIdx.x;
    if (idx >= n * 16) return;
    int j = idx >> 4;
    int c4 = idx & 15;
    int cb = c4 * 4;
    float dj = dinv[j];
    float sn = dj * dj;
    H4 s; s.u2 = *(const uint2*)&Yin[(size_t)j * NG + cb];
    float a0 = sn * __half2float(s.h[0]);
    float a1 = sn * __half2float(s.h[1]);
    float a2 = sn * __half2float(s.h[2]);
    float a3 = sn * __half2float(s.h[3]);
    unsigned e0 = row_start[j], e1 = row_start[j + 1];
    unsigned e = e0;
    for (; e + 2 <= e1; e += 2) {
        uint2 p0 = euv[e], p1 = euv[e + 1];
        float v0 = u_as_f(p0.y), v1 = u_as_f(p1.y);
        H4 m0; m0.u2 = *(const uint2*)&Yin[(size_t)(p0.x & 0x1FFFFu) * NG + cb];
        H4 m1; m1.u2 = *(const uint2*)&Yin[(size_t)(p1.x & 0x1FFFFu) * NG + cb];
        a0 += v0 * __half2float(m0.h[0]) + v1 * __half2float(m1.h[0]);
        a1 += v0 * __half2float(m0.h[1]) + v1 * __half2float(m1.h[1]);
        a2 += v0 * __half2float(m0.h[2]) + v1 * __half2float(m1.h[2]);
        a3 += v0 * __half2float(m0.h[3]) + v1 * __half2float(m1.h[3]);
    }
    if (e < e1) {
        uint2 p0 = euv[e];
        float v0 = u_as_f(p0.y);
        H4 m0; m0.u2 = *(const uint2*)&Yin[(size_t)(p0.x & 0x1FFFFu) * NG + cb];
        a0 += v0 * __half2float(m0.h[0]);
        a1 += v0 * __half2float(m0.h[1]);
        a2 += v0 * __half2float(m0.h[2]);
        a3 += v0 * __half2float(m0.h[3]);
    }
    H4 o;
    o.h[0] = __float2half(a0); o.h[1] = __float2half(a1);
    o.h[2] = __float2half(a2); o.h[3] = __float2half(a3);
    *(uint2*)&Yout[(size_t)j * NG + cb] = o.u2;
}

// ---------------- column sums (fp16 input), XCC-replicated output ----------------
__global__ __launch_bounds__(256) void k_colsumh(const __half* __restrict__ Y,
                                                 float* __restrict__ su8, int n) {
    __shared__ float red[16][NG];
    int t = threadIdx.x;
    int cg = t & 15;
    int sr = t >> 4;
    float a0 = 0.f, a1 = 0.f, a2 = 0.f, a3 = 0.f;
    int stride = gridDim.x * 16;
    for (int j = blockIdx.x * 16 + sr; j < n; j += stride) {
        H4 v; v.u2 = *(const uint2*)&Y[(size_t)j * NG + cg * 4];
        a0 += __half2float(v.h[0]);
        a1 += __half2float(v.h[1]);
        a2 += __half2float(v.h[2]);
        a3 += __half2float(v.h[3]);
    }
    red[sr][cg * 4 + 0] = a0;
    red[sr][cg * 4 + 1] = a1;
    red[sr][cg * 4 + 2] = a2;
    red[sr][cg * 4 + 3] = a3;
    __syncthreads();
    if (t < NG) {
        float s = 0.f;
#pragma unroll
        for (int q = 0; q < 16; ++q) s += red[q][t];
        int r = xcc_id();
        __hip_atomic_fetch_add(&su8[r * NG + t], s,
                               __ATOMIC_RELAXED, __HIP_MEMORY_SCOPE_WORKGROUP);
    }
}

// ---------------- atom table: LDS histogram (vocab 41), small flush ----------------
__global__ __launch_bounds__(256) void k_ta(const __half* __restrict__ Y3,
                                            const int* __restrict__ x,
                                            float* __restrict__ ta, int n) {
    __shared__ float lta[41 * NG];
    int t = threadIdx.x;
    for (int i = t; i < 41 * NG; i += 256) lta[i] = 0.f;
    __syncthreads();
    int g = t & 63;
    int sv = t >> 6;
    for (int j = blockIdx.x * 4 + sv; j < n; j += gridDim.x * 4) {
        float y = __half2float(Y3[(size_t)j * NG + g]);
        int a = x[2 * j];
        atomicAdd(&lta[a * NG + g], y);
    }
    __syncthreads();
    for (int i = t; i < 41 * NG; i += 256) atomicAdd(&ta[i], lta[i]);
}

// ---------------- fused word contraction ----------------
// Block b owns words [b*WB, (b+1)*WB). Phase A: wave-per-word gather-sum of Y3 rows
// (sorted order -> no atomics). Phase B: rank-1 updates acc[g][75c] with wave-uniform
// scalar wt loads. Flush: plain stores into per-block partial (no atomics).
__global__ __launch_bounds__(256) void k_wfused(const __half* __restrict__ Y3,
                                                const unsigned* __restrict__ sorted,
                                                const unsigned* __restrict__ wstart,
                                                const float* __restrict__ wt,
                                                float* __restrict__ Gpart) {
    __shared__ float tl[WB * NG];
    int b = blockIdx.x;
    int w0 = b * WB;
    int t = threadIdx.x;
    int g = t & 63;
    int wv = t >> 6;
    // Phase A: per-word column sums
    for (int w = wv; w < WB; w += 4) {
        unsigned i0 = wstart[w0 + w], i1 = wstart[w0 + w + 1];
        float s = 0.f;
        for (unsigned idx = i0; idx < i1; ++idx) {
            unsigned j = sorted[idx];
            s += __half2float(Y3[(size_t)j * NG + g]);
        }
        tl[w * NG + g] = s;
    }
    __syncthreads();
    // Phase B: acc[g][c], c = qs*75 + i
    int qs = __builtin_amdgcn_readfirstlane(wv);
    const float* wtb = wt + (size_t)w0 * 300 + qs * 75;
    float acc[75];
#pragma unroll
    for (int i = 0; i < 75; ++i) acc[i] = 0.f;
    for (int w = 0; w < WB; ++w) {
        float tg = tl[w * NG + g];
        const float* wr = wtb + w * 300;
#pragma unroll
        for (int i = 0; i < 75; ++i) acc[i] += tg * wr[i];
    }
    // flush: per-block partial, plain stores
    float* gp = Gpart + (size_t)b * (NG * 300) + g * 300 + qs * 75;
#pragma unroll
    for (int i = 0; i < 75; ++i) gp[i] = acc[i];
}

// reduce partials into G0 (atomicAdd; G0 zeroed, agemm adds later)
__global__ __launch_bounds__(256) void k_greduce(const float* __restrict__ Gpart,
                                                 float* __restrict__ G0) {
    int k = blockIdx.x * 256 + threadIdx.x;
    if (k >= NG * 300) return;
    int p0 = (NWB * blockIdx.y) / 4;
    int p1 = (NWB * (blockIdx.y + 1)) / 4;
    float s = 0.f;
    for (int p = p0; p < p1; ++p) s += Gpart[(size_t)p * (NG * 300) + k];
    atomicAdd(&G0[k], s);
}

// ---------------- atom contraction: K=41 ----------------
__global__ __launch_bounds__(256) void k_agemm(const float* __restrict__ T,
                                               const float* __restrict__ Tab,
                                               float* __restrict__ G0) {
    int j = blockIdx.x * 256 + threadIdx.x;
    if (j >= NG * 300) return;
    int g = j / 300, c = j - g * 300;
    float acc = 0.f;
#pragma unroll
    for (int k = 0; k < 41; ++k) acc += T[(size_t)k * NG + g] * Tab[(size_t)k * 300 + c];
    atomicAdd(&G0[j], acc);
}

// ---------------- small GEMM split-k ----------------
__global__ __launch_bounds__(256) void k_smm(const float* __restrict__ A,
                                             const float* __restrict__ W,
                                             float* __restrict__ C) {
    int j = blockIdx.x * 256 + threadIdx.x;
    if (j >= NG * 300) return;
    int g = j / 300, c = j - g * 300;
    int k0 = blockIdx.y * 60;
    float acc = 0.f;
#pragma unroll 1
    for (int k = k0; k < k0 + 60; k += 4) {
        float a0 = A[g * 300 + k + 0], a1 = A[g * 300 + k + 1];
        float a2 = A[g * 300 + k + 2], a3 = A[g * 300 + k + 3];
        float w0 = W[(k + 0) * 300 + c], w1 = W[(k + 1) * 300 + c];
        float w2 = W[(k + 2) * 300 + c], w3 = W[(k + 3) * 300 + c];
        acc += a0 * w0 + a1 * w1 + a2 * w2 + a3 * w3;
    }
    atomicAdd(&C[j], acc);
}

// ---------------- vector-matrix ----------------
__global__ __launch_bounds__(256) void k_vec(const float* __restrict__ vin,
                                             const float* __restrict__ W,
                                             float* __restrict__ r_out) {
    int c = blockIdx.x * 256 + threadIdx.x;
    if (c >= 300) return;
    int k0 = blockIdx.y * 75;
    float acc = 0.f;
    for (int k = k0; k < k0 + 75; ++k) acc += vin[k] * W[k * 300 + c];
    atomicAdd(&r_out[c], acc);
}

// ---------------- final assembly ----------------
__global__ __launch_bounds__(256) void k_out(const float* __restrict__ T3,
                                             const float* __restrict__ su1,
                                             const float* __restrict__ su2,
                                             const int* __restrict__ gstart,
                                             const float* __restrict__ r1,
                                             const float* __restrict__ r2,
                                             const float* __restrict__ b,
                                             float* __restrict__ out) {
    int j = blockIdx.x * 256 + threadIdx.x;
    if (j >= NG * 300) return;
    int g = j / 300, c = j - g * 300;
    int cnt = gstart[g + 1] - gstart[g];
    float s1 = 0.f, s2 = 0.f;
#pragma unroll
    for (int r = 0; r < 8; ++r) {
        s1 += su1[r * NG + g];
        s2 += su2[r * NG + g];
    }
    float v = T3[j] + s2 * r2[c] + s1 * r1[c] + (float)cnt * b[c];
    out[j] = v / (float)(cnt > 0 ? cnt : 1);
}

// ---------------- launch ----------------
extern "C" void kernel_launch(void* const* d_in, const int* in_sizes, int n_in,
                              void* d_out, int out_size, void* d_ws, size_t ws_size,
                              hipStream_t stream) {
    const int*   x     = (const int*)d_in[0];
    const int*   ei    = (const int*)d_in[1];
    const int*   batch = (const int*)d_in[2];
    const float* at    = (const float*)d_in[3];
    const float* wt    = (const float*)d_in[4];
    const float* W     = (const float*)d_in[5];
    const float* b     = (const float*)d_in[6];

    const int n = in_sizes[0] / 2;   // 100000
    const int e = in_sizes[1] / 2;   // 800000

    char* ws = (char*)d_ws;
    size_t off = 0;
    auto carve = [&](size_t bytes) {
        void* p = ws + off;
        off += (bytes + 255) & ~(size_t)255;
        return p;
    };
    __half*   Y1        = (__half*)carve((size_t)n * NG * 2);
    __half*   Y2        = (__half*)carve((size_t)n * NG * 2);
    __half*   Y3        = (__half*)carve((size_t)n * NG * 2);
    uint2*    euv       = (uint2*)carve((size_t)e * 8);
    float*    dinv      = (float*)carve((size_t)n * 4);
    unsigned* counts_src= (unsigned*)carve((size_t)n * 4);
    unsigned* row_start = (unsigned*)carve((size_t)(n + 1) * 4);
    unsigned* partials  = (unsigned*)carve(1024 * 4);
    int*      gstart    = (int*)carve(65 * 4);
    unsigned* wstart    = (unsigned*)carve((size_t)(VOC + 1) * 4);
    unsigned* sorted    = (unsigned*)carve((size_t)n * 4);
    // ---- zero region B ----
    char*     zB0       = (char*)carve(0);
    float*    su1       = (float*)carve((size_t)8 * NG * 4);
    float*    su2       = (float*)carve((size_t)8 * NG * 4);
    float*    ta        = (float*)carve((size_t)41 * NG * 4);
    float*    G0        = (float*)carve((size_t)NG * 300 * 4);
    float*    r1        = (float*)carve(300 * 4);
    float*    r2        = (float*)carve(300 * 4);
    float*    T1        = (float*)carve((size_t)NG * 300 * 4);
    float*    T2        = (float*)carve((size_t)NG * 300 * 4);
    float*    T3        = (float*)carve((size_t)NG * 300 * 4);
    char*     zB1       = (char*)carve(0);

    const int* src = ei;
    const int* dst = ei + e;

    // aliases (lifetime-disjoint):
    //  edge replicas in Y1/Y2 (dead before k_y1 writes Y1)
    //  word replicas in Y3    (dead before yprop#2 writes Y3)
    //  Gpart in Y1+Y2         (Y1/Y2 dead after colsumh(Y2)/yprop#2; 19.2MB <= 25.6MB)
    unsigned* rep_in  = (unsigned*)Y1;
    unsigned* rep_src = (unsigned*)Y2;
    unsigned* rep_w   = (unsigned*)Y3;
    float*    Gpart   = (float*)Y1;

    hipMemsetAsync(zB0, 0, (size_t)(zB1 - zB0), stream);

    const int npairs = (n + 1) / 2;
    const int NRng   = (n + RSZ - 1) / RSZ;        // 8
    const int chunk  = (e + NC_MS - 1) / NC_MS;    // 12500
    const int wchunk = (n + NC_W - 1) / NC_W;      // 782

    // edge reverse-CSR (multi-split, no device atomics)
    k_mscount<<<NRng * NC_MS, 256, 0, stream>>>(src, dst, rep_in, rep_src, e, n, chunk, npairs);
    k_msreduce<<<(npairs + 255) / 256, 256, 0, stream>>>(rep_in, rep_src, dinv, counts_src, n, npairs);
    int NB = (n + 1023) / 1024;      // 98
    k_blocksum<<<NB, 256, 0, stream>>>(counts_src, partials, n);
    k_scanpartials<<<1, 128, 0, stream>>>(partials, NB);
    k_scanblock<<<NB, 256, 0, stream>>>(counts_src, partials, row_start, n);
    k_msfill<<<NRng * NC_MS, 256, 0, stream>>>(src, dst, batch, row_start, rep_src, dinv, euv, e, n, chunk, npairs);
    k_gstart<<<1, 128, 0, stream>>>(batch, gstart, n, NGRAPH_C);

    // word counting sort (counts_src / partials reused; rep_w aliases Y3)
    k_wmscount<<<NC_W, 256, 0, stream>>>(x, rep_w, n, wchunk);
    k_wmsreduce<<<(VOCP + 255) / 256, 256, 0, stream>>>(rep_w, counts_src);
    int NBW = (VOC + 1023) / 1024;   // 10
    k_blocksum<<<NBW, 256, 0, stream>>>(counts_src, partials, VOC);
    k_scanpartials<<<1, 128, 0, stream>>>(partials, NBW);
    k_scanblock<<<NBW, 256, 0, stream>>>(counts_src, partials, wstart, VOC);
    k_wmsfill<<<NC_W, 256, 0, stream>>>(x, wstart, rep_w, sorted, n, wchunk);

    // indicator propagation: Y1 -> Y2 -> Y3 (fp16)
    int yb = (n * 16 + 255) / 256;   // 6250
    k_y1<<<yb, 256, 0, stream>>>(batch, dinv, row_start, euv, Y1, n);
    k_colsumh<<<512, 256, 0, stream>>>(Y1, su1, n);
    k_yprop<<<yb, 256, 0, stream>>>(Y1, dinv, row_start, euv, Y2, n);
    k_colsumh<<<512, 256, 0, stream>>>(Y2, su2, n);
    k_yprop<<<yb, 256, 0, stream>>>(Y2, dinv, row_start, euv, Y3, n);

    // contractions -> G0 = Y3^T H0
    k_ta<<<128, 256, 0, stream>>>(Y3, x, ta, n);
    k_wfused<<<NWB, 256, 0, stream>>>(Y3, sorted, wstart, wt, Gpart);
    {
        dim3 gr((NG * 300 + 255) / 256, 4);
        k_greduce<<<gr, 256, 0, stream>>>(Gpart, G0);
    }
    k_agemm<<<(NG * 300 + 255) / 256, 256, 0, stream>>>(ta, at, G0);

    // W chain: T3 = G0 * W^3
    {
        dim3 gs((NG * 300 + 255) / 256, 5);
        k_smm<<<gs, 256, 0, stream>>>(G0, W, T1);
        k_smm<<<gs, 256, 0, stream>>>(T1, W, T2);
        k_smm<<<gs, 256, 0, stream>>>(T2, W, T3);
        dim3 gv(2, 4);
        k_vec<<<gv, 256, 0, stream>>>(b, W, r1);
        k_vec<<<gv, 256, 0, stream>>>(r1, W, r2);
    }

    k_out<<<(NG * 300 + 255) / 256, 256, 0, stream>>>(T3, su1, su2, gstart, r1, r2, b, (float*)d_out);
}

// Round 4
// 372.317 us; speedup vs baseline: 1.2559x; 1.2559x over previous
//
#include <hip/hip_runtime.h>
#include <hip/hip_fp16.h>

#define NG 64              // graphs (= Y feature width)
#define NGRAPH_C 64

// edge multi-split geometry
#define RSZ 12500          // nodes per range (8 ranges for n=100000)
#define RSZP 6250          // packed u16 pairs per range
#define NC_MS 64           // edge chunks

// word contraction geometry
#define VOC 10000
#define KPAD 10240         // padded K for wgemm (80 chunks of 128)
#define NKC 80             // split-k chunks
#define WGK 128            // K per chunk

// ---- bit casts ----
__device__ __forceinline__ unsigned f_as_u(float f) { union { float f; unsigned u; } c; c.f = f; return c.u; }
__device__ __forceinline__ float u_as_f(unsigned u) { union { unsigned u; float f; } c; c.u = u; return c.f; }

// XCD id (0..7)
__device__ __forceinline__ int xcc_id() {
    unsigned x;
    asm volatile("s_getreg_b32 %0, hwreg(HW_REG_XCC_ID)" : "=s"(x));
    return (int)(x & 7u);
}

union H4 { uint2 u2; __half h[4]; };

// ---------------- edge multi-split count ----------------
__global__ __launch_bounds__(256) void k_mscount(const int* __restrict__ src, const int* __restrict__ dst,
                                                 unsigned* __restrict__ rep_in,
                                                 unsigned* __restrict__ rep_src,
                                                 int e, int n, int chunk, int npairs) {
    __shared__ unsigned hin[RSZP];
    __shared__ unsigned hsrc[RSZP];
    int c = blockIdx.x % NC_MS;
    int r = blockIdx.x / NC_MS;
    int base = r * RSZ;
    int t = threadIdx.x;
    for (int w = t; w < RSZP; w += 256) { hin[w] = 0u; hsrc[w] = 0u; }
    __syncthreads();
    int e0 = c * chunk, e1 = min(e, e0 + chunk);
    for (int i = e0 + t; i < e1; i += 256) {
        int s = src[i], d = dst[i];
        unsigned ud = (unsigned)(d - base);
        unsigned us = (unsigned)(s - base);
        if (ud < (unsigned)RSZ) atomicAdd(&hin[ud >> 1], 1u << ((ud & 1) * 16));
        if (us < (unsigned)RSZ) atomicAdd(&hsrc[us >> 1], 1u << ((us & 1) * 16));
    }
    __syncthreads();
    int lim = min(RSZ, n - base);
    if (lim <= 0) return;
    int plim = (lim + 1) >> 1;
    unsigned* gin  = rep_in  + (size_t)c * npairs + (base >> 1);
    unsigned* gsrc = rep_src + (size_t)c * npairs + (base >> 1);
    for (int w = t; w < plim; w += 256) { gin[w] = hin[w]; gsrc[w] = hsrc[w]; }
}

__global__ __launch_bounds__(256) void k_msreduce(const unsigned* __restrict__ rep_in,
                                                  unsigned* __restrict__ rep_src,   // -> pref
                                                  float* __restrict__ dinv,
                                                  unsigned* __restrict__ counts_src,
                                                  int n, int npairs) {
    int i2 = blockIdx.x * 256 + threadIdx.x;
    if (i2 >= npairs) return;
    unsigned slo = 0, shi = 0, rlo = 0, rhi = 0;
#pragma unroll 4
    for (int c = 0; c < NC_MS; ++c) {
        unsigned vi = rep_in[(size_t)c * npairs + i2];
        slo += vi & 0xFFFFu; shi += vi >> 16;
        unsigned vs = rep_src[(size_t)c * npairs + i2];
        rep_src[(size_t)c * npairs + i2] = rlo | (rhi << 16);
        rlo += vs & 0xFFFFu; rhi += vs >> 16;
    }
    int i = i2 * 2;
    dinv[i] = rsqrtf((float)(slo + 1u));
    counts_src[i] = rlo;
    if (i + 1 < n) {
        dinv[i + 1] = rsqrtf((float)(shi + 1u));
        counts_src[i + 1] = rhi;
    }
}

// ---------------- 2-level exclusive scan ----------------
__global__ __launch_bounds__(256) void k_blocksum(const unsigned* __restrict__ counts,
                                                  unsigned* __restrict__ partials, int n) {
    __shared__ unsigned s[256];
    int base = blockIdx.x * 1024;
    unsigned sum = 0;
    for (int j = threadIdx.x; j < 1024; j += 256) {
        int i = base + j;
        sum += (i < n) ? counts[i] : 0u;
    }
    s[threadIdx.x] = sum;
    __syncthreads();
    for (int off = 128; off > 0; off >>= 1) {
        if (threadIdx.x < (unsigned)off) s[threadIdx.x] += s[threadIdx.x + off];
        __syncthreads();
    }
    if (threadIdx.x == 0) partials[blockIdx.x] = s[0];
}

__global__ __launch_bounds__(128) void k_scanpartials(unsigned* __restrict__ partials, int nb) {
    __shared__ unsigned s[128];
    int t = threadIdx.x;
    s[t] = (t < nb) ? partials[t] : 0u;
    __syncthreads();
    if (t == 0) {
        unsigned run = 0;
        for (int i = 0; i < nb; ++i) { unsigned v = s[i]; s[i] = run; run += v; }
    }
    __syncthreads();
    if (t < nb) partials[t] = s[t];
}

__global__ __launch_bounds__(256) void k_scanblock(const unsigned* __restrict__ counts,
                                                   const unsigned* __restrict__ partials,
                                                   unsigned* __restrict__ row_start, int n) {
    __shared__ unsigned s[256];
    int base = blockIdx.x * 1024;
    int t = threadIdx.x;
    unsigned v[4];
    unsigned tsum = 0;
#pragma unroll
    for (int j = 0; j < 4; ++j) {
        int i = base + t * 4 + j;
        v[j] = (i < n) ? counts[i] : 0u;
        tsum += v[j];
    }
    s[t] = tsum;
    __syncthreads();
    for (int off = 1; off < 256; off <<= 1) {
        unsigned x = (t >= off) ? s[t - off] : 0u;
        __syncthreads();
        s[t] += x;
        __syncthreads();
    }
    unsigned excl = (t > 0 ? s[t - 1] : 0u) + partials[blockIdx.x];
#pragma unroll
    for (int j = 0; j < 4; ++j) {
        int i = base + t * 4 + j;
        if (i < n) {
            row_start[i] = excl;
            excl += v[j];
            if (i == n - 1) row_start[n] = excl;
        }
    }
}

// ---------------- edge multi-split fill ----------------
__global__ __launch_bounds__(256) void k_msfill(const int* __restrict__ src, const int* __restrict__ dst,
                                                const int* __restrict__ batch,
                                                const unsigned* __restrict__ row_start,
                                                const unsigned* __restrict__ pref,
                                                const float* __restrict__ dinv,
                                                uint2* __restrict__ euv,
                                                int e, int n, int chunk, int npairs) {
    __shared__ unsigned cur[RSZP];
    int c = blockIdx.x % NC_MS;
    int r = blockIdx.x / NC_MS;
    int base = r * RSZ;
    int t = threadIdx.x;
    for (int w = t; w < RSZP; w += 256) cur[w] = 0u;
    __syncthreads();
    int e0 = c * chunk, e1 = min(e, e0 + chunk);
    const unsigned* prefc = pref + (size_t)c * npairs;
    for (int i = e0 + t; i < e1; i += 256) {
        int s = src[i];
        unsigned us = (unsigned)(s - base);
        if (us < (unsigned)RSZ) {
            int d = dst[i];
            unsigned sh = (us & 1) * 16;
            unsigned old = atomicAdd(&cur[us >> 1], 1u << sh);
            unsigned slot = (old >> sh) & 0xFFFFu;
            unsigned p16 = (prefc[(unsigned)s >> 1] >> ((s & 1) * 16)) & 0xFFFFu;
            unsigned pos = row_start[s] + p16 + slot;
            uint2 pv;
            pv.x = (unsigned)d | ((unsigned)batch[d] << 17);
            pv.y = f_as_u(dinv[s] * dinv[d]);
            euv[pos] = pv;
        }
    }
}

// ---------------- word counting sort (order-free: atomic cursor) ----------------
// 0.1M device atomics over 10000 counters ~= 4-5 us at the measured memory-side
// atomic rate; 64x fewer than k_bucket's 6.4M.
__global__ __launch_bounds__(256) void k_wcount(const int* __restrict__ x,
                                                unsigned* __restrict__ wcnt, int n) {
    int j = blockIdx.x * 256 + threadIdx.x;
    if (j >= n) return;
    atomicAdd(&wcnt[x[2 * j + 1]], 1u);
}

__global__ __launch_bounds__(256) void k_wfill(const int* __restrict__ x,
                                               const unsigned* __restrict__ wstart,
                                               unsigned* __restrict__ wcur,
                                               unsigned* __restrict__ sorted, int n) {
    int j = blockIdx.x * 256 + threadIdx.x;
    if (j >= n) return;
    int w = x[2 * j + 1];
    unsigned pos = wstart[w] + atomicAdd(&wcur[w], 1u);
    sorted[pos] = (unsigned)j;
}

// ---------------- per-word column sums: tw[w][g] (plain stores, 2500 blocks) ----------------
__global__ __launch_bounds__(256) void k_twfill(const __half* __restrict__ Y3,
                                                const unsigned* __restrict__ sorted,
                                                const unsigned* __restrict__ wstart,
                                                float* __restrict__ tw) {
    int w = blockIdx.x * 4 + (threadIdx.x >> 6);
    int g = threadIdx.x & 63;
    if (w >= VOC) return;
    unsigned i0 = wstart[w], i1 = wstart[w + 1];
    float s = 0.f;
    unsigned i = i0;
    for (; i + 2 <= i1; i += 2) {
        unsigned j0 = sorted[i], j1 = sorted[i + 1];
        s += __half2float(Y3[(size_t)j0 * NG + g]) + __half2float(Y3[(size_t)j1 * NG + g]);
    }
    if (i < i1) {
        unsigned j0 = sorted[i];
        s += __half2float(Y3[(size_t)j0 * NG + g]);
    }
    tw[(size_t)w * NG + g] = s;
}

// ---------------- graph boundaries (batch sorted) ----------------
__global__ __launch_bounds__(128) void k_gstart(const int* __restrict__ batch,
                                                int* __restrict__ gstart, int n, int ngraph) {
    int g = threadIdx.x;
    if (g > ngraph) return;
    if (g == ngraph) { gstart[g] = n; return; }
    int lo = 0, hi = n;
    while (lo < hi) {
        int mid = (lo + hi) >> 1;
        if (batch[mid] < g) lo = mid + 1; else hi = mid;
    }
    gstart[g] = lo;
}

// ---------------- hop 1 (fp16 out) ----------------
__global__ __launch_bounds__(256) void k_y1(const int* __restrict__ batch,
                                            const float* __restrict__ dinv,
                                            const unsigned* __restrict__ row_start,
                                            const uint2* __restrict__ euv,
                                            __half* __restrict__ Y1, int n) {
    int idx = blockIdx.x * 256 + threadIdx.x;
    if (idx >= n * 16) return;
    int j = idx >> 4;
    int c4 = idx & 15;
    int cb = c4 * 4;
    float a0 = 0.f, a1 = 0.f, a2 = 0.f, a3 = 0.f;
    {
        int bj = batch[j];
        float dj = dinv[j];
        float sn = dj * dj;
        a0 += (bj == cb + 0) ? sn : 0.f;
        a1 += (bj == cb + 1) ? sn : 0.f;
        a2 += (bj == cb + 2) ? sn : 0.f;
        a3 += (bj == cb + 3) ? sn : 0.f;
    }
    unsigned e0 = row_start[j], e1 = row_start[j + 1];
    for (unsigned e = e0; e < e1; ++e) {
        uint2 p = euv[e];
        int bd = (int)(p.x >> 17);
        float v = u_as_f(p.y);
        a0 += (bd == cb + 0) ? v : 0.f;
        a1 += (bd == cb + 1) ? v : 0.f;
        a2 += (bd == cb + 2) ? v : 0.f;
        a3 += (bd == cb + 3) ? v : 0.f;
    }
    H4 o;
    o.h[0] = __float2half(a0); o.h[1] = __float2half(a1);
    o.h[2] = __float2half(a2); o.h[3] = __float2half(a3);
    *(uint2*)&Y1[(size_t)j * NG + cb] = o.u2;
}

// ---------------- Y-hop fp16 -> fp16 ----------------
__global__ __launch_bounds__(256) void k_yprop(const __half* __restrict__ Yin,
                                               const float* __restrict__ dinv,
                                               const unsigned* __restrict__ row_start,
                                               const uint2* __restrict__ euv,
                                               __half* __restrict__ Yout, int n) {
    int idx = blockIdx.x * 256 + threadIdx.x;
    if (idx >= n * 16) return;
    int j = idx >> 4;
    int c4 = idx & 15;
    int cb = c4 * 4;
    float dj = dinv[j];
    float sn = dj * dj;
    H4 s; s.u2 = *(const uint2*)&Yin[(size_t)j * NG + cb];
    float a0 = sn * __half2float(s.h[0]);
    float a1 = sn * __half2float(s.h[1]);
    float a2 = sn * __half2float(s.h[2]);
    float a3 = sn * __half2float(s.h[3]);
    unsigned e0 = row_start[j], e1 = row_start[j + 1];
    unsigned e = e0;
    for (; e + 2 <= e1; e += 2) {
        uint2 p0 = euv[e], p1 = euv[e + 1];
        float v0 = u_as_f(p0.y), v1 = u_as_f(p1.y);
        H4 m0; m0.u2 = *(const uint2*)&Yin[(size_t)(p0.x & 0x1FFFFu) * NG + cb];
        H4 m1; m1.u2 = *(const uint2*)&Yin[(size_t)(p1.x & 0x1FFFFu) * NG + cb];
        a0 += v0 * __half2float(m0.h[0]) + v1 * __half2float(m1.h[0]);
        a1 += v0 * __half2float(m0.h[1]) + v1 * __half2float(m1.h[1]);
        a2 += v0 * __half2float(m0.h[2]) + v1 * __half2float(m1.h[2]);
        a3 += v0 * __half2float(m0.h[3]) + v1 * __half2float(m1.h[3]);
    }
    if (e < e1) {
        uint2 p0 = euv[e];
        float v0 = u_as_f(p0.y);
        H4 m0; m0.u2 = *(const uint2*)&Yin[(size_t)(p0.x & 0x1FFFFu) * NG + cb];
        a0 += v0 * __half2float(m0.h[0]);
        a1 += v0 * __half2float(m0.h[1]);
        a2 += v0 * __half2float(m0.h[2]);
        a3 += v0 * __half2float(m0.h[3]);
    }
    H4 o;
    o.h[0] = __float2half(a0); o.h[1] = __float2half(a1);
    o.h[2] = __float2half(a2); o.h[3] = __float2half(a3);
    *(uint2*)&Yout[(size_t)j * NG + cb] = o.u2;
}

// ---------------- column sums (fp16 input), XCC-replicated output ----------------
__global__ __launch_bounds__(256) void k_colsumh(const __half* __restrict__ Y,
                                                 float* __restrict__ su8, int n) {
    __shared__ float red[16][NG];
    int t = threadIdx.x;
    int cg = t & 15;
    int sr = t >> 4;
    float a0 = 0.f, a1 = 0.f, a2 = 0.f, a3 = 0.f;
    int stride = gridDim.x * 16;
    for (int j = blockIdx.x * 16 + sr; j < n; j += stride) {
        H4 v; v.u2 = *(const uint2*)&Y[(size_t)j * NG + cg * 4];
        a0 += __half2float(v.h[0]);
        a1 += __half2float(v.h[1]);
        a2 += __half2float(v.h[2]);
        a3 += __half2float(v.h[3]);
    }
    red[sr][cg * 4 + 0] = a0;
    red[sr][cg * 4 + 1] = a1;
    red[sr][cg * 4 + 2] = a2;
    red[sr][cg * 4 + 3] = a3;
    __syncthreads();
    if (t < NG) {
        float s = 0.f;
#pragma unroll
        for (int q = 0; q < 16; ++q) s += red[q][t];
        int r = xcc_id();
        __hip_atomic_fetch_add(&su8[r * NG + t], s,
                               __ATOMIC_RELAXED, __HIP_MEMORY_SCOPE_WORKGROUP);
    }
}

// ---------------- atom table: LDS histogram (vocab 41), small flush ----------------
__global__ __launch_bounds__(256) void k_ta(const __half* __restrict__ Y3,
                                            const int* __restrict__ x,
                                            float* __restrict__ ta, int n) {
    __shared__ float lta[41 * NG];
    int t = threadIdx.x;
    for (int i = t; i < 41 * NG; i += 256) lta[i] = 0.f;
    __syncthreads();
    int g = t & 63;
    int sv = t >> 6;
    for (int j = blockIdx.x * 4 + sv; j < n; j += gridDim.x * 4) {
        float y = __half2float(Y3[(size_t)j * NG + g]);
        int a = x[2 * j];
        atomicAdd(&lta[a * NG + g], y);
    }
    __syncthreads();
    for (int i = t; i < 41 * NG; i += 256) atomicAdd(&ta[i], lta[i]);
}

// ---------------- tiled word contraction: Gpart[kc] = tw_chunk^T @ wt_chunk ----------------
// 5 c-tiles x 80 k-chunks of 128 = 400 blocks; per-block output is a disjoint
// 64x64 sub-tile of its k-chunk partial -> plain stores, no atomics.
__global__ __launch_bounds__(256) void k_wgemm2(const float* __restrict__ T,    // [KPAD][64]
                                                const float* __restrict__ Tab,  // [10000][300]
                                                float* __restrict__ Gpart) {
    __shared__ float Asm[32 * 64];
    __shared__ float Bsm[32 * 64];
    const int t = threadIdx.x;
    const int tg = t >> 4;
    const int tc = t & 15;
    const int c0 = blockIdx.x * 64;
    const int kb = blockIdx.y * WGK;

    float acc[4][4] = {};

    for (int sub = 0; sub < WGK / 32; ++sub) {
        int kbase = kb + sub * 32;
#pragma unroll
        for (int r2 = 0; r2 < 2; ++r2) {
            int idx4 = r2 * 256 + t;
            int k = idx4 >> 4, g4 = idx4 & 15;
            float4 v = *(const float4*)&T[(size_t)(kbase + k) * 64 + g4 * 4];
            *(float4*)&Asm[k * 64 + g4 * 4] = v;
        }
#pragma unroll
        for (int r2 = 0; r2 < 2; ++r2) {
            int idx4 = r2 * 256 + t;
            int k = idx4 >> 4, c4i = idx4 & 15;
            int gk = kbase + k;
            int cb2 = c0 + c4i * 4;
            float4 v;
            if (gk < VOC && cb2 + 3 < 300) {
                v = *(const float4*)&Tab[(size_t)gk * 300 + cb2];
            } else {
                float tmp[4];
#pragma unroll
                for (int q = 0; q < 4; ++q)
                    tmp[q] = (gk < VOC && cb2 + q < 300) ? Tab[(size_t)gk * 300 + cb2 + q] : 0.f;
                v.x = tmp[0]; v.y = tmp[1]; v.z = tmp[2]; v.w = tmp[3];
            }
            *(float4*)&Bsm[k * 64 + c4i * 4] = v;
        }
        __syncthreads();
#pragma unroll 8
        for (int k = 0; k < 32; ++k) {
            float4 a4 = *(const float4*)&Asm[k * 64 + tg * 4];
            float4 b4 = *(const float4*)&Bsm[k * 64 + tc * 4];
            float a[4] = {a4.x, a4.y, a4.z, a4.w};
            float b[4] = {b4.x, b4.y, b4.z, b4.w};
#pragma unroll
            for (int i = 0; i < 4; ++i)
#pragma unroll
                for (int jj = 0; jj < 4; ++jj) acc[i][jj] += a[i] * b[jj];
        }
        __syncthreads();
    }

    float* gp = Gpart + (size_t)blockIdx.y * (NG * 300);
#pragma unroll
    for (int i = 0; i < 4; ++i) {
        int g = tg * 4 + i;
#pragma unroll
        for (int jj = 0; jj < 4; ++jj) {
            int c = c0 + tc * 4 + jj;
            if (c < 300) gp[g * 300 + c] = acc[i][jj];
        }
    }
}

// reduce k-chunk partials into G0 (few atomics; G0 zeroed)
__global__ __launch_bounds__(256) void k_greduce(const float* __restrict__ Gpart,
                                                 float* __restrict__ G0) {
    int k = blockIdx.x * 256 + threadIdx.x;
    if (k >= NG * 300) return;
    int p0 = blockIdx.y * (NKC / 8);
    int p1 = p0 + (NKC / 8);
    float s = 0.f;
    for (int p = p0; p < p1; ++p) s += Gpart[(size_t)p * (NG * 300) + k];
    atomicAdd(&G0[k], s);
}

// ---------------- atom contraction: K=41 ----------------
__global__ __launch_bounds__(256) void k_agemm(const float* __restrict__ T,
                                               const float* __restrict__ Tab,
                                               float* __restrict__ G0) {
    int j = blockIdx.x * 256 + threadIdx.x;
    if (j >= NG * 300) return;
    int g = j / 300, c = j - g * 300;
    float acc = 0.f;
#pragma unroll
    for (int k = 0; k < 41; ++k) acc += T[(size_t)k * NG + g] * Tab[(size_t)k * 300 + c];
    atomicAdd(&G0[j], acc);
}

// ---------------- small GEMM split-k ----------------
__global__ __launch_bounds__(256) void k_smm(const float* __restrict__ A,
                                             const float* __restrict__ W,
                                             float* __restrict__ C) {
    int j = blockIdx.x * 256 + threadIdx.x;
    if (j >= NG * 300) return;
    int g = j / 300, c = j - g * 300;
    int k0 = blockIdx.y * 60;
    float acc = 0.f;
#pragma unroll 1
    for (int k = k0; k < k0 + 60; k += 4) {
        float a0 = A[g * 300 + k + 0], a1 = A[g * 300 + k + 1];
        float a2 = A[g * 300 + k + 2], a3 = A[g * 300 + k + 3];
        float w0 = W[(k + 0) * 300 + c], w1 = W[(k + 1) * 300 + c];
        float w2 = W[(k + 2) * 300 + c], w3 = W[(k + 3) * 300 + c];
        acc += a0 * w0 + a1 * w1 + a2 * w2 + a3 * w3;
    }
    atomicAdd(&C[j], acc);
}

// ---------------- vector-matrix ----------------
__global__ __launch_bounds__(256) void k_vec(const float* __restrict__ vin,
                                             const float* __restrict__ W,
                                             float* __restrict__ r_out) {
    int c = blockIdx.x * 256 + threadIdx.x;
    if (c >= 300) return;
    int k0 = blockIdx.y * 75;
    float acc = 0.f;
    for (int k = k0; k < k0 + 75; ++k) acc += vin[k] * W[k * 300 + c];
    atomicAdd(&r_out[c], acc);
}

// ---------------- final assembly ----------------
__global__ __launch_bounds__(256) void k_out(const float* __restrict__ T3,
                                             const float* __restrict__ su1,
                                             const float* __restrict__ su2,
                                             const int* __restrict__ gstart,
                                             const float* __restrict__ r1,
                                             const float* __restrict__ r2,
                                             const float* __restrict__ b,
                                             float* __restrict__ out) {
    int j = blockIdx.x * 256 + threadIdx.x;
    if (j >= NG * 300) return;
    int g = j / 300, c = j - g * 300;
    int cnt = gstart[g + 1] - gstart[g];
    float s1 = 0.f, s2 = 0.f;
#pragma unroll
    for (int r = 0; r < 8; ++r) {
        s1 += su1[r * NG + g];
        s2 += su2[r * NG + g];
    }
    float v = T3[j] + s2 * r2[c] + s1 * r1[c] + (float)cnt * b[c];
    out[j] = v / (float)(cnt > 0 ? cnt : 1);
}

// ---------------- launch ----------------
extern "C" void kernel_launch(void* const* d_in, const int* in_sizes, int n_in,
                              void* d_out, int out_size, void* d_ws, size_t ws_size,
                              hipStream_t stream) {
    const int*   x     = (const int*)d_in[0];
    const int*   ei    = (const int*)d_in[1];
    const int*   batch = (const int*)d_in[2];
    const float* at    = (const float*)d_in[3];
    const float* wt    = (const float*)d_in[4];
    const float* W     = (const float*)d_in[5];
    const float* b     = (const float*)d_in[6];

    const int n = in_sizes[0] / 2;   // 100000
    const int e = in_sizes[1] / 2;   // 800000

    char* ws = (char*)d_ws;
    size_t off = 0;
    auto carve = [&](size_t bytes) {
        void* p = ws + off;
        off += (bytes + 255) & ~(size_t)255;
        return p;
    };
    __half*   Y1        = (__half*)carve((size_t)n * NG * 2);
    __half*   Y2        = (__half*)carve((size_t)n * NG * 2);
    __half*   Y3        = (__half*)carve((size_t)n * NG * 2);
    uint2*    euv       = (uint2*)carve((size_t)e * 8);
    float*    dinv      = (float*)carve((size_t)n * 4);
    unsigned* counts_src= (unsigned*)carve((size_t)n * 4);
    unsigned* row_start = (unsigned*)carve((size_t)(n + 1) * 4);
    unsigned* partials  = (unsigned*)carve(1024 * 4);
    int*      gstart    = (int*)carve(65 * 4);
    unsigned* wstart    = (unsigned*)carve((size_t)(VOC + 1) * 4);
    unsigned* sorted    = (unsigned*)carve((size_t)n * 4);
    // ---- zero region B ----
    char*     zB0       = (char*)carve(0);
    float*    su1       = (float*)carve((size_t)8 * NG * 4);
    float*    su2       = (float*)carve((size_t)8 * NG * 4);
    float*    ta        = (float*)carve((size_t)41 * NG * 4);
    float*    tw        = (float*)carve((size_t)KPAD * NG * 4);   // pad rows must be zero
    float*    G0        = (float*)carve((size_t)NG * 300 * 4);
    float*    r1        = (float*)carve(300 * 4);
    float*    r2        = (float*)carve(300 * 4);
    float*    T1        = (float*)carve((size_t)NG * 300 * 4);
    float*    T2        = (float*)carve((size_t)NG * 300 * 4);
    float*    T3        = (float*)carve((size_t)NG * 300 * 4);
    unsigned* wcnt      = (unsigned*)carve((size_t)VOC * 4);
    unsigned* wcur      = (unsigned*)carve((size_t)VOC * 4);
    char*     zB1       = (char*)carve(0);

    const int* src = ei;
    const int* dst = ei + e;

    // aliases (lifetime-disjoint):
    //  edge replicas in Y1/Y2 (dead before k_y1 writes Y1 / before yprop#1 writes Y2)
    //  Gpart (80*64*300*4 = 24.6MB) in Y1+Y2 (both dead after yprop#2 reads Y2)
    unsigned* rep_in  = (unsigned*)Y1;
    unsigned* rep_src = (unsigned*)Y2;
    float*    Gpart   = (float*)Y1;

    hipMemsetAsync(zB0, 0, (size_t)(zB1 - zB0), stream);

    const int npairs = (n + 1) / 2;
    const int NRng   = (n + RSZ - 1) / RSZ;        // 8
    const int chunk  = (e + NC_MS - 1) / NC_MS;    // 12500

    // edge reverse-CSR (multi-split, no device atomics)
    k_mscount<<<NRng * NC_MS, 256, 0, stream>>>(src, dst, rep_in, rep_src, e, n, chunk, npairs);
    k_msreduce<<<(npairs + 255) / 256, 256, 0, stream>>>(rep_in, rep_src, dinv, counts_src, n, npairs);
    int NB = (n + 1023) / 1024;      // 98
    k_blocksum<<<NB, 256, 0, stream>>>(counts_src, partials, n);
    k_scanpartials<<<1, 128, 0, stream>>>(partials, NB);
    k_scanblock<<<NB, 256, 0, stream>>>(counts_src, partials, row_start, n);
    k_msfill<<<NRng * NC_MS, 256, 0, stream>>>(src, dst, batch, row_start, rep_src, dinv, euv, e, n, chunk, npairs);
    k_gstart<<<1, 128, 0, stream>>>(batch, gstart, n, NGRAPH_C);

    // word counting sort (atomic cursor; order within word irrelevant)
    int nb256 = (n + 255) / 256;
    k_wcount<<<nb256, 256, 0, stream>>>(x, wcnt, n);
    int NBW = (VOC + 1023) / 1024;   // 10
    k_blocksum<<<NBW, 256, 0, stream>>>(wcnt, partials, VOC);
    k_scanpartials<<<1, 128, 0, stream>>>(partials, NBW);
    k_scanblock<<<NBW, 256, 0, stream>>>(wcnt, partials, wstart, VOC);
    k_wfill<<<nb256, 256, 0, stream>>>(x, wstart, wcur, sorted, n);

    // indicator propagation: Y1 -> Y2 -> Y3 (fp16)
    int yb = (n * 16 + 255) / 256;   // 6250
    k_y1<<<yb, 256, 0, stream>>>(batch, dinv, row_start, euv, Y1, n);
    k_colsumh<<<512, 256, 0, stream>>>(Y1, su1, n);
    k_yprop<<<yb, 256, 0, stream>>>(Y1, dinv, row_start, euv, Y2, n);
    k_colsumh<<<512, 256, 0, stream>>>(Y2, su2, n);
    k_yprop<<<yb, 256, 0, stream>>>(Y2, dinv, row_start, euv, Y3, n);

    // contractions -> G0 = Y3^T H0
    k_ta<<<256, 256, 0, stream>>>(Y3, x, ta, n);
    k_twfill<<<(VOC + 3) / 4, 256, 0, stream>>>(Y3, sorted, wstart, tw);
    {
        dim3 gw(5, NKC);   // 5 c-tiles x 80 k-chunks of 128
        k_wgemm2<<<gw, 256, 0, stream>>>(tw, wt, Gpart);
        dim3 gr((NG * 300 + 255) / 256, 8);
        k_greduce<<<gr, 256, 0, stream>>>(Gpart, G0);
    }
    k_agemm<<<(NG * 300 + 255) / 256, 256, 0, stream>>>(ta, at, G0);

    // W chain: T3 = G0 * W^3
    {
        dim3 gs((NG * 300 + 255) / 256, 5);
        k_smm<<<gs, 256, 0, stream>>>(G0, W, T1);
        k_smm<<<gs, 256, 0, stream>>>(T1, W, T2);
        k_smm<<<gs, 256, 0, stream>>>(T2, W, T3);
        dim3 gv(2, 4);
        k_vec<<<gv, 256, 0, stream>>>(b, W, r1);
        k_vec<<<gv, 256, 0, stream>>>(r1, W, r2);
    }

    k_out<<<(NG * 300 + 255) / 256, 256, 0, stream>>>(T3, su1, su2, gstart, r1, r2, b, (float*)d_out);
}

// Round 5
// 342.804 us; speedup vs baseline: 1.3640x; 1.0861x over previous
//
#include <hip/hip_runtime.h>
#include <hip/hip_fp16.h>

#define NG 64              // graphs (= Y feature width)
#define NGRAPH_C 64

// edge multi-split geometry
#define RSZ 12500          // nodes per range (8 ranges for n=100000)
#define RSZP 6250          // packed u16 pairs per range
#define NC_MS 64           // edge chunks
#define MSB 1024           // threads/block for count/fill (occupancy: 2 blk/CU x 16 waves)

// word contraction geometry
#define VOC 10000
#define KPAD 10240         // padded K for wgemm (80 chunks of 128)
#define NKC 80             // split-k chunks
#define WGK 128            // K per chunk

// ---- bit casts ----
__device__ __forceinline__ unsigned f_as_u(float f) { union { float f; unsigned u; } c; c.f = f; return c.u; }
__device__ __forceinline__ float u_as_f(unsigned u) { union { unsigned u; float f; } c; c.u = u; return c.f; }

// XCD id (0..7)
__device__ __forceinline__ int xcc_id() {
    unsigned x;
    asm volatile("s_getreg_b32 %0, hwreg(HW_REG_XCC_ID)" : "=s"(x));
    return (int)(x & 7u);
}

union H4 { uint2 u2; __half h[4]; };

// ---------------- edge multi-split count (1024 thr: latency hidden by 16 waves) ----------------
__global__ __launch_bounds__(MSB) void k_mscount(const int* __restrict__ src, const int* __restrict__ dst,
                                                 unsigned* __restrict__ rep_in,
                                                 unsigned* __restrict__ rep_src,
                                                 int e, int n, int chunk, int npairs) {
    __shared__ unsigned hin[RSZP];
    __shared__ unsigned hsrc[RSZP];
    int c = blockIdx.x % NC_MS;
    int r = blockIdx.x / NC_MS;
    int base = r * RSZ;
    int t = threadIdx.x;
    for (int w = t; w < RSZP; w += MSB) { hin[w] = 0u; hsrc[w] = 0u; }
    __syncthreads();
    int e0 = c * chunk, e1 = min(e, e0 + chunk);
    for (int i = e0 + t; i < e1; i += MSB) {
        int s = src[i], d = dst[i];
        unsigned ud = (unsigned)(d - base);
        unsigned us = (unsigned)(s - base);
        if (ud < (unsigned)RSZ) atomicAdd(&hin[ud >> 1], 1u << ((ud & 1) * 16));
        if (us < (unsigned)RSZ) atomicAdd(&hsrc[us >> 1], 1u << ((us & 1) * 16));
    }
    __syncthreads();
    int lim = min(RSZ, n - base);
    if (lim <= 0) return;
    int plim = (lim + 1) >> 1;
    unsigned* gin  = rep_in  + (size_t)c * npairs + (base >> 1);
    unsigned* gsrc = rep_src + (size_t)c * npairs + (base >> 1);
    for (int w = t; w < plim; w += MSB) { gin[w] = hin[w]; gsrc[w] = hsrc[w]; }
}

__global__ __launch_bounds__(256) void k_msreduce(const unsigned* __restrict__ rep_in,
                                                  unsigned* __restrict__ rep_src,   // -> pref
                                                  float* __restrict__ dinv,
                                                  unsigned* __restrict__ counts_src,
                                                  int n, int npairs) {
    int i2 = blockIdx.x * 256 + threadIdx.x;
    if (i2 >= npairs) return;
    unsigned slo = 0, shi = 0, rlo = 0, rhi = 0;
#pragma unroll 4
    for (int c = 0; c < NC_MS; ++c) {
        unsigned vi = rep_in[(size_t)c * npairs + i2];
        slo += vi & 0xFFFFu; shi += vi >> 16;
        unsigned vs = rep_src[(size_t)c * npairs + i2];
        rep_src[(size_t)c * npairs + i2] = rlo | (rhi << 16);
        rlo += vs & 0xFFFFu; rhi += vs >> 16;
    }
    int i = i2 * 2;
    dinv[i] = rsqrtf((float)(slo + 1u));
    counts_src[i] = rlo;
    if (i + 1 < n) {
        dinv[i + 1] = rsqrtf((float)(shi + 1u));
        counts_src[i + 1] = rhi;
    }
}

// ---------------- 2-level exclusive scan ----------------
__global__ __launch_bounds__(256) void k_blocksum(const unsigned* __restrict__ counts,
                                                  unsigned* __restrict__ partials, int n) {
    __shared__ unsigned s[256];
    int base = blockIdx.x * 1024;
    unsigned sum = 0;
    for (int j = threadIdx.x; j < 1024; j += 256) {
        int i = base + j;
        sum += (i < n) ? counts[i] : 0u;
    }
    s[threadIdx.x] = sum;
    __syncthreads();
    for (int off = 128; off > 0; off >>= 1) {
        if (threadIdx.x < (unsigned)off) s[threadIdx.x] += s[threadIdx.x + off];
        __syncthreads();
    }
    if (threadIdx.x == 0) partials[blockIdx.x] = s[0];
}

__global__ __launch_bounds__(128) void k_scanpartials(unsigned* __restrict__ partials, int nb) {
    __shared__ unsigned s[128];
    int t = threadIdx.x;
    s[t] = (t < nb) ? partials[t] : 0u;
    __syncthreads();
    if (t == 0) {
        unsigned run = 0;
        for (int i = 0; i < nb; ++i) { unsigned v = s[i]; s[i] = run; run += v; }
    }
    __syncthreads();
    if (t < nb) partials[t] = s[t];
}

__global__ __launch_bounds__(256) void k_scanblock(const unsigned* __restrict__ counts,
                                                   const unsigned* __restrict__ partials,
                                                   unsigned* __restrict__ row_start, int n) {
    __shared__ unsigned s[256];
    int base = blockIdx.x * 1024;
    int t = threadIdx.x;
    unsigned v[4];
    unsigned tsum = 0;
#pragma unroll
    for (int j = 0; j < 4; ++j) {
        int i = base + t * 4 + j;
        v[j] = (i < n) ? counts[i] : 0u;
        tsum += v[j];
    }
    s[t] = tsum;
    __syncthreads();
    for (int off = 1; off < 256; off <<= 1) {
        unsigned x = (t >= off) ? s[t - off] : 0u;
        __syncthreads();
        s[t] += x;
        __syncthreads();
    }
    unsigned excl = (t > 0 ? s[t - 1] : 0u) + partials[blockIdx.x];
#pragma unroll
    for (int j = 0; j < 4; ++j) {
        int i = base + t * 4 + j;
        if (i < n) {
            row_start[i] = excl;
            excl += v[j];
            if (i == n - 1) row_start[n] = excl;
        }
    }
}

// ---------------- edge multi-split fill (1024 thr) ----------------
__global__ __launch_bounds__(MSB) void k_msfill(const int* __restrict__ src, const int* __restrict__ dst,
                                                const int* __restrict__ batch,
                                                const unsigned* __restrict__ row_start,
                                                const unsigned* __restrict__ pref,
                                                const float* __restrict__ dinv,
                                                uint2* __restrict__ euv,
                                                int e, int n, int chunk, int npairs) {
    __shared__ unsigned cur[RSZP];
    int c = blockIdx.x % NC_MS;
    int r = blockIdx.x / NC_MS;
    int base = r * RSZ;
    int t = threadIdx.x;
    for (int w = t; w < RSZP; w += MSB) cur[w] = 0u;
    __syncthreads();
    int e0 = c * chunk, e1 = min(e, e0 + chunk);
    const unsigned* prefc = pref + (size_t)c * npairs;
    for (int i = e0 + t; i < e1; i += MSB) {
        int s = src[i];
        unsigned us = (unsigned)(s - base);
        if (us < (unsigned)RSZ) {
            int d = dst[i];
            unsigned sh = (us & 1) * 16;
            unsigned old = atomicAdd(&cur[us >> 1], 1u << sh);
            unsigned slot = (old >> sh) & 0xFFFFu;
            unsigned p16 = (prefc[(unsigned)s >> 1] >> ((s & 1) * 16)) & 0xFFFFu;
            unsigned pos = row_start[s] + p16 + slot;
            uint2 pv;
            pv.x = (unsigned)d | ((unsigned)batch[d] << 17);
            pv.y = f_as_u(dinv[s] * dinv[d]);
            euv[pos] = pv;
        }
    }
}

// ---------------- word counting sort (order-free: atomic cursor) ----------------
__global__ __launch_bounds__(256) void k_wcount(const int* __restrict__ x,
                                                unsigned* __restrict__ wcnt, int n) {
    int j = blockIdx.x * 256 + threadIdx.x;
    if (j >= n) return;
    atomicAdd(&wcnt[x[2 * j + 1]], 1u);
}

__global__ __launch_bounds__(256) void k_wfill(const int* __restrict__ x,
                                               const unsigned* __restrict__ wstart,
                                               unsigned* __restrict__ wcur,
                                               unsigned* __restrict__ sorted, int n) {
    int j = blockIdx.x * 256 + threadIdx.x;
    if (j >= n) return;
    int w = x[2 * j + 1];
    unsigned pos = wstart[w] + atomicAdd(&wcur[w], 1u);
    sorted[pos] = (unsigned)j;
}

// ---------------- per-word column sums: tw[w][g] (plain stores) ----------------
__global__ __launch_bounds__(256) void k_twfill(const __half* __restrict__ Y3,
                                                const unsigned* __restrict__ sorted,
                                                const unsigned* __restrict__ wstart,
                                                float* __restrict__ tw) {
    int w = blockIdx.x * 4 + (threadIdx.x >> 6);
    int g = threadIdx.x & 63;
    if (w >= VOC) return;
    unsigned i0 = wstart[w], i1 = wstart[w + 1];
    float s = 0.f;
    unsigned i = i0;
    for (; i + 2 <= i1; i += 2) {
        unsigned j0 = sorted[i], j1 = sorted[i + 1];
        s += __half2float(Y3[(size_t)j0 * NG + g]) + __half2float(Y3[(size_t)j1 * NG + g]);
    }
    if (i < i1) {
        unsigned j0 = sorted[i];
        s += __half2float(Y3[(size_t)j0 * NG + g]);
    }
    tw[(size_t)w * NG + g] = s;
}

// ---------------- graph boundaries (batch sorted) ----------------
__global__ __launch_bounds__(128) void k_gstart(const int* __restrict__ batch,
                                                int* __restrict__ gstart, int n, int ngraph) {
    int g = threadIdx.x;
    if (g > ngraph) return;
    if (g == ngraph) { gstart[g] = n; return; }
    int lo = 0, hi = n;
    while (lo < hi) {
        int mid = (lo + hi) >> 1;
        if (batch[mid] < g) lo = mid + 1; else hi = mid;
    }
    gstart[g] = lo;
}

// ---------------- hop 1 (fp16 out) ----------------
__global__ __launch_bounds__(256) void k_y1(const int* __restrict__ batch,
                                            const float* __restrict__ dinv,
                                            const unsigned* __restrict__ row_start,
                                            const uint2* __restrict__ euv,
                                            __half* __restrict__ Y1, int n) {
    int idx = blockIdx.x * 256 + threadIdx.x;
    if (idx >= n * 16) return;
    int j = idx >> 4;
    int c4 = idx & 15;
    int cb = c4 * 4;
    float a0 = 0.f, a1 = 0.f, a2 = 0.f, a3 = 0.f;
    {
        int bj = batch[j];
        float dj = dinv[j];
        float sn = dj * dj;
        a0 += (bj == cb + 0) ? sn : 0.f;
        a1 += (bj == cb + 1) ? sn : 0.f;
        a2 += (bj == cb + 2) ? sn : 0.f;
        a3 += (bj == cb + 3) ? sn : 0.f;
    }
    unsigned e0 = row_start[j], e1 = row_start[j + 1];
    for (unsigned e = e0; e < e1; ++e) {
        uint2 p = euv[e];
        int bd = (int)(p.x >> 17);
        float v = u_as_f(p.y);
        a0 += (bd == cb + 0) ? v : 0.f;
        a1 += (bd == cb + 1) ? v : 0.f;
        a2 += (bd == cb + 2) ? v : 0.f;
        a3 += (bd == cb + 3) ? v : 0.f;
    }
    H4 o;
    o.h[0] = __float2half(a0); o.h[1] = __float2half(a1);
    o.h[2] = __float2half(a2); o.h[3] = __float2half(a3);
    *(uint2*)&Y1[(size_t)j * NG + cb] = o.u2;
}

// ---------------- Y-hop fp16 -> fp16 (4-wide unrolled gather for MLP) ----------------
__global__ __launch_bounds__(256) void k_yprop(const __half* __restrict__ Yin,
                                               const float* __restrict__ dinv,
                                               const unsigned* __restrict__ row_start,
                                               const uint2* __restrict__ euv,
                                               __half* __restrict__ Yout, int n) {
    int idx = blockIdx.x * 256 + threadIdx.x;
    if (idx >= n * 16) return;
    int j = idx >> 4;
    int c4 = idx & 15;
    int cb = c4 * 4;
    float dj = dinv[j];
    float sn = dj * dj;
    H4 s; s.u2 = *(const uint2*)&Yin[(size_t)j * NG + cb];
    float a0 = sn * __half2float(s.h[0]);
    float a1 = sn * __half2float(s.h[1]);
    float a2 = sn * __half2float(s.h[2]);
    float a3 = sn * __half2float(s.h[3]);
    unsigned e0 = row_start[j], e1 = row_start[j + 1];
    unsigned e = e0;
    for (; e + 4 <= e1; e += 4) {
        uint2 p0 = euv[e], p1 = euv[e + 1], p2 = euv[e + 2], p3 = euv[e + 3];
        float v0 = u_as_f(p0.y), v1 = u_as_f(p1.y);
        float v2 = u_as_f(p2.y), v3 = u_as_f(p3.y);
        H4 m0; m0.u2 = *(const uint2*)&Yin[(size_t)(p0.x & 0x1FFFFu) * NG + cb];
        H4 m1; m1.u2 = *(const uint2*)&Yin[(size_t)(p1.x & 0x1FFFFu) * NG + cb];
        H4 m2; m2.u2 = *(const uint2*)&Yin[(size_t)(p2.x & 0x1FFFFu) * NG + cb];
        H4 m3; m3.u2 = *(const uint2*)&Yin[(size_t)(p3.x & 0x1FFFFu) * NG + cb];
        a0 += v0 * __half2float(m0.h[0]) + v1 * __half2float(m1.h[0])
            + v2 * __half2float(m2.h[0]) + v3 * __half2float(m3.h[0]);
        a1 += v0 * __half2float(m0.h[1]) + v1 * __half2float(m1.h[1])
            + v2 * __half2float(m2.h[1]) + v3 * __half2float(m3.h[1]);
        a2 += v0 * __half2float(m0.h[2]) + v1 * __half2float(m1.h[2])
            + v2 * __half2float(m2.h[2]) + v3 * __half2float(m3.h[2]);
        a3 += v0 * __half2float(m0.h[3]) + v1 * __half2float(m1.h[3])
            + v2 * __half2float(m2.h[3]) + v3 * __half2float(m3.h[3]);
    }
    for (; e < e1; ++e) {
        uint2 p0 = euv[e];
        float v0 = u_as_f(p0.y);
        H4 m0; m0.u2 = *(const uint2*)&Yin[(size_t)(p0.x & 0x1FFFFu) * NG + cb];
        a0 += v0 * __half2float(m0.h[0]);
        a1 += v0 * __half2float(m0.h[1]);
        a2 += v0 * __half2float(m0.h[2]);
        a3 += v0 * __half2float(m0.h[3]);
    }
    H4 o;
    o.h[0] = __float2half(a0); o.h[1] = __float2half(a1);
    o.h[2] = __float2half(a2); o.h[3] = __float2half(a3);
    *(uint2*)&Yout[(size_t)j * NG + cb] = o.u2;
}

// ---------------- column sums (fp16 input), XCC-replicated output ----------------
__global__ __launch_bounds__(256) void k_colsumh(const __half* __restrict__ Y,
                                                 float* __restrict__ su8, int n) {
    __shared__ float red[16][NG];
    int t = threadIdx.x;
    int cg = t & 15;
    int sr = t >> 4;
    float a0 = 0.f, a1 = 0.f, a2 = 0.f, a3 = 0.f;
    int stride = gridDim.x * 16;
    for (int j = blockIdx.x * 16 + sr; j < n; j += stride) {
        H4 v; v.u2 = *(const uint2*)&Y[(size_t)j * NG + cg * 4];
        a0 += __half2float(v.h[0]);
        a1 += __half2float(v.h[1]);
        a2 += __half2float(v.h[2]);
        a3 += __half2float(v.h[3]);
    }
    red[sr][cg * 4 + 0] = a0;
    red[sr][cg * 4 + 1] = a1;
    red[sr][cg * 4 + 2] = a2;
    red[sr][cg * 4 + 3] = a3;
    __syncthreads();
    if (t < NG) {
        float s = 0.f;
#pragma unroll
        for (int q = 0; q < 16; ++q) s += red[q][t];
        int r = xcc_id();
        __hip_atomic_fetch_add(&su8[r * NG + t], s,
                               __ATOMIC_RELAXED, __HIP_MEMORY_SCOPE_WORKGROUP);
    }
}

// ---------------- atom table: LDS histogram (vocab 41), small flush ----------------
__global__ __launch_bounds__(256) void k_ta(const __half* __restrict__ Y3,
                                            const int* __restrict__ x,
                                            float* __restrict__ ta, int n) {
    __shared__ float lta[41 * NG];
    int t = threadIdx.x;
    for (int i = t; i < 41 * NG; i += 256) lta[i] = 0.f;
    __syncthreads();
    int g = t & 63;
    int sv = t >> 6;
    for (int j = blockIdx.x * 4 + sv; j < n; j += gridDim.x * 4) {
        float y = __half2float(Y3[(size_t)j * NG + g]);
        int a = x[2 * j];
        atomicAdd(&lta[a * NG + g], y);
    }
    __syncthreads();
    for (int i = t; i < 41 * NG; i += 256) atomicAdd(&ta[i], lta[i]);
}

// ---------------- tiled word contraction: Gpart[kc] = tw_chunk^T @ wt_chunk ----------------
__global__ __launch_bounds__(256) void k_wgemm2(const float* __restrict__ T,    // [KPAD][64]
                                                const float* __restrict__ Tab,  // [10000][300]
                                                float* __restrict__ Gpart) {
    __shared__ float Asm[32 * 64];
    __shared__ float Bsm[32 * 64];
    const int t = threadIdx.x;
    const int tg = t >> 4;
    const int tc = t & 15;
    const int c0 = blockIdx.x * 64;
    const int kb = blockIdx.y * WGK;

    float acc[4][4] = {};

    for (int sub = 0; sub < WGK / 32; ++sub) {
        int kbase = kb + sub * 32;
#pragma unroll
        for (int r2 = 0; r2 < 2; ++r2) {
            int idx4 = r2 * 256 + t;
            int k = idx4 >> 4, g4 = idx4 & 15;
            float4 v = *(const float4*)&T[(size_t)(kbase + k) * 64 + g4 * 4];
            *(float4*)&Asm[k * 64 + g4 * 4] = v;
        }
#pragma unroll
        for (int r2 = 0; r2 < 2; ++r2) {
            int idx4 = r2 * 256 + t;
            int k = idx4 >> 4, c4i = idx4 & 15;
            int gk = kbase + k;
            int cb2 = c0 + c4i * 4;
            float4 v;
            if (gk < VOC && cb2 + 3 < 300) {
                v = *(const float4*)&Tab[(size_t)gk * 300 + cb2];
            } else {
                float tmp[4];
#pragma unroll
                for (int q = 0; q < 4; ++q)
                    tmp[q] = (gk < VOC && cb2 + q < 300) ? Tab[(size_t)gk * 300 + cb2 + q] : 0.f;
                v.x = tmp[0]; v.y = tmp[1]; v.z = tmp[2]; v.w = tmp[3];
            }
            *(float4*)&Bsm[k * 64 + c4i * 4] = v;
        }
        __syncthreads();
#pragma unroll 8
        for (int k = 0; k < 32; ++k) {
            float4 a4 = *(const float4*)&Asm[k * 64 + tg * 4];
            float4 b4 = *(const float4*)&Bsm[k * 64 + tc * 4];
            float a[4] = {a4.x, a4.y, a4.z, a4.w};
            float b[4] = {b4.x, b4.y, b4.z, b4.w};
#pragma unroll
            for (int i = 0; i < 4; ++i)
#pragma unroll
                for (int jj = 0; jj < 4; ++jj) acc[i][jj] += a[i] * b[jj];
        }
        __syncthreads();
    }

    float* gp = Gpart + (size_t)blockIdx.y * (NG * 300);
#pragma unroll
    for (int i = 0; i < 4; ++i) {
        int g = tg * 4 + i;
#pragma unroll
        for (int jj = 0; jj < 4; ++jj) {
            int c = c0 + tc * 4 + jj;
            if (c < 300) gp[g * 300 + c] = acc[i][jj];
        }
    }
}

// reduce k-chunk partials into G0 (few atomics; G0 zeroed)
__global__ __launch_bounds__(256) void k_greduce(const float* __restrict__ Gpart,
                                                 float* __restrict__ G0) {
    int k = blockIdx.x * 256 + threadIdx.x;
    if (k >= NG * 300) return;
    int p0 = blockIdx.y * (NKC / 8);
    int p1 = p0 + (NKC / 8);
    float s = 0.f;
    for (int p = p0; p < p1; ++p) s += Gpart[(size_t)p * (NG * 300) + k];
    atomicAdd(&G0[k], s);
}

// ---------------- atom contraction: K=41 ----------------
__global__ __launch_bounds__(256) void k_agemm(const float* __restrict__ T,
                                               const float* __restrict__ Tab,
                                               float* __restrict__ G0) {
    int j = blockIdx.x * 256 + threadIdx.x;
    if (j >= NG * 300) return;
    int g = j / 300, c = j - g * 300;
    float acc = 0.f;
#pragma unroll
    for (int k = 0; k < 41; ++k) acc += T[(size_t)k * NG + g] * Tab[(size_t)k * 300 + c];
    atomicAdd(&G0[j], acc);
}

// ---------------- small GEMM split-k ----------------
__global__ __launch_bounds__(256) void k_smm(const float* __restrict__ A,
                                             const float* __restrict__ W,
                                             float* __restrict__ C) {
    int j = blockIdx.x * 256 + threadIdx.x;
    if (j >= NG * 300) return;
    int g = j / 300, c = j - g * 300;
    int k0 = blockIdx.y * 60;
    float acc = 0.f;
#pragma unroll 1
    for (int k = k0; k < k0 + 60; k += 4) {
        float a0 = A[g * 300 + k + 0], a1 = A[g * 300 + k + 1];
        float a2 = A[g * 300 + k + 2], a3 = A[g * 300 + k + 3];
        float w0 = W[(k + 0) * 300 + c], w1 = W[(k + 1) * 300 + c];
        float w2 = W[(k + 2) * 300 + c], w3 = W[(k + 3) * 300 + c];
        acc += a0 * w0 + a1 * w1 + a2 * w2 + a3 * w3;
    }
    atomicAdd(&C[j], acc);
}

// ---------------- vector-matrix ----------------
__global__ __launch_bounds__(256) void k_vec(const float* __restrict__ vin,
                                             const float* __restrict__ W,
                                             float* __restrict__ r_out) {
    int c = blockIdx.x * 256 + threadIdx.x;
    if (c >= 300) return;
    int k0 = blockIdx.y * 75;
    float acc = 0.f;
    for (int k = k0; k < k0 + 75; ++k) acc += vin[k] * W[k * 300 + c];
    atomicAdd(&r_out[c], acc);
}

// ---------------- final assembly ----------------
__global__ __launch_bounds__(256) void k_out(const float* __restrict__ T3,
                                             const float* __restrict__ su1,
                                             const float* __restrict__ su2,
                                             const int* __restrict__ gstart,
                                             const float* __restrict__ r1,
                                             const float* __restrict__ r2,
                                             const float* __restrict__ b,
                                             float* __restrict__ out) {
    int j = blockIdx.x * 256 + threadIdx.x;
    if (j >= NG * 300) return;
    int g = j / 300, c = j - g * 300;
    int cnt = gstart[g + 1] - gstart[g];
    float s1 = 0.f, s2 = 0.f;
#pragma unroll
    for (int r = 0; r < 8; ++r) {
        s1 += su1[r * NG + g];
        s2 += su2[r * NG + g];
    }
    float v = T3[j] + s2 * r2[c] + s1 * r1[c] + (float)cnt * b[c];
    out[j] = v / (float)(cnt > 0 ? cnt : 1);
}

// ---------------- launch ----------------
extern "C" void kernel_launch(void* const* d_in, const int* in_sizes, int n_in,
                              void* d_out, int out_size, void* d_ws, size_t ws_size,
                              hipStream_t stream) {
    const int*   x     = (const int*)d_in[0];
    const int*   ei    = (const int*)d_in[1];
    const int*   batch = (const int*)d_in[2];
    const float* at    = (const float*)d_in[3];
    const float* wt    = (const float*)d_in[4];
    const float* W     = (const float*)d_in[5];
    const float* b     = (const float*)d_in[6];

    const int n = in_sizes[0] / 2;   // 100000
    const int e = in_sizes[1] / 2;   // 800000

    char* ws = (char*)d_ws;
    size_t off = 0;
    auto carve = [&](size_t bytes) {
        void* p = ws + off;
        off += (bytes + 255) & ~(size_t)255;
        return p;
    };
    __half*   Y1        = (__half*)carve((size_t)n * NG * 2);
    __half*   Y2        = (__half*)carve((size_t)n * NG * 2);
    __half*   Y3        = (__half*)carve((size_t)n * NG * 2);
    uint2*    euv       = (uint2*)carve((size_t)e * 8);
    float*    dinv      = (float*)carve((size_t)n * 4);
    unsigned* counts_src= (unsigned*)carve((size_t)n * 4);
    unsigned* row_start = (unsigned*)carve((size_t)(n + 1) * 4);
    unsigned* partials  = (unsigned*)carve(1024 * 4);
    int*      gstart    = (int*)carve(65 * 4);
    unsigned* wstart    = (unsigned*)carve((size_t)(VOC + 1) * 4);
    unsigned* sorted    = (unsigned*)carve((size_t)n * 4);
    // ---- zero region B ----
    char*     zB0       = (char*)carve(0);
    float*    su1       = (float*)carve((size_t)8 * NG * 4);
    float*    su2       = (float*)carve((size_t)8 * NG * 4);
    float*    ta        = (float*)carve((size_t)41 * NG * 4);
    float*    tw        = (float*)carve((size_t)KPAD * NG * 4);   // pad rows must be zero
    float*    G0        = (float*)carve((size_t)NG * 300 * 4);
    float*    r1        = (float*)carve(300 * 4);
    float*    r2        = (float*)carve(300 * 4);
    float*    T1        = (float*)carve((size_t)NG * 300 * 4);
    float*    T2        = (float*)carve((size_t)NG * 300 * 4);
    float*    T3        = (float*)carve((size_t)NG * 300 * 4);
    unsigned* wcnt      = (unsigned*)carve((size_t)VOC * 4);
    unsigned* wcur      = (unsigned*)carve((size_t)VOC * 4);
    char*     zB1       = (char*)carve(0);

    const int* src = ei;
    const int* dst = ei + e;

    // aliases (lifetime-disjoint):
    //  edge replicas in Y1/Y2 (dead before k_y1 writes Y1 / before yprop#1 writes Y2)
    //  Gpart (80*64*300*4 = 24.6MB) in Y1+Y2 (both dead after yprop#2 reads Y2)
    unsigned* rep_in  = (unsigned*)Y1;
    unsigned* rep_src = (unsigned*)Y2;
    float*    Gpart   = (float*)Y1;

    hipMemsetAsync(zB0, 0, (size_t)(zB1 - zB0), stream);

    const int npairs = (n + 1) / 2;
    const int NRng   = (n + RSZ - 1) / RSZ;        // 8
    const int chunk  = (e + NC_MS - 1) / NC_MS;    // 12500

    // edge reverse-CSR (multi-split, no device atomics; 1024-thr blocks for occupancy)
    k_mscount<<<NRng * NC_MS, MSB, 0, stream>>>(src, dst, rep_in, rep_src, e, n, chunk, npairs);
    k_msreduce<<<(npairs + 255) / 256, 256, 0, stream>>>(rep_in, rep_src, dinv, counts_src, n, npairs);
    int NB = (n + 1023) / 1024;      // 98
    k_blocksum<<<NB, 256, 0, stream>>>(counts_src, partials, n);
    k_scanpartials<<<1, 128, 0, stream>>>(partials, NB);
    k_scanblock<<<NB, 256, 0, stream>>>(counts_src, partials, row_start, n);
    k_msfill<<<NRng * NC_MS, MSB, 0, stream>>>(src, dst, batch, row_start, rep_src, dinv, euv, e, n, chunk, npairs);
    k_gstart<<<1, 128, 0, stream>>>(batch, gstart, n, NGRAPH_C);

    // word counting sort (atomic cursor; order within word irrelevant)
    int nb256 = (n + 255) / 256;
    k_wcount<<<nb256, 256, 0, stream>>>(x, wcnt, n);
    int NBW = (VOC + 1023) / 1024;   // 10
    k_blocksum<<<NBW, 256, 0, stream>>>(wcnt, partials, VOC);
    k_scanpartials<<<1, 128, 0, stream>>>(partials, NBW);
    k_scanblock<<<NBW, 256, 0, stream>>>(wcnt, partials, wstart, VOC);
    k_wfill<<<nb256, 256, 0, stream>>>(x, wstart, wcur, sorted, n);

    // indicator propagation: Y1 -> Y2 -> Y3 (fp16)
    int yb = (n * 16 + 255) / 256;   // 6250
    k_y1<<<yb, 256, 0, stream>>>(batch, dinv, row_start, euv, Y1, n);
    k_colsumh<<<512, 256, 0, stream>>>(Y1, su1, n);
    k_yprop<<<yb, 256, 0, stream>>>(Y1, dinv, row_start, euv, Y2, n);
    k_colsumh<<<512, 256, 0, stream>>>(Y2, su2, n);
    k_yprop<<<yb, 256, 0, stream>>>(Y2, dinv, row_start, euv, Y3, n);

    // contractions -> G0 = Y3^T H0
    k_ta<<<256, 256, 0, stream>>>(Y3, x, ta, n);
    k_twfill<<<(VOC + 3) / 4, 256, 0, stream>>>(Y3, sorted, wstart, tw);
    {
        dim3 gw(5, NKC);   // 5 c-tiles x 80 k-chunks of 128
        k_wgemm2<<<gw, 256, 0, stream>>>(tw, wt, Gpart);
        dim3 gr((NG * 300 + 255) / 256, 8);
        k_greduce<<<gr, 256, 0, stream>>>(Gpart, G0);
    }
    k_agemm<<<(NG * 300 + 255) / 256, 256, 0, stream>>>(ta, at, G0);

    // W chain: T3 = G0 * W^3
    {
        dim3 gs((NG * 300 + 255) / 256, 5);
        k_smm<<<gs, 256, 0, stream>>>(G0, W, T1);
        k_smm<<<gs, 256, 0, stream>>>(T1, W, T2);
        k_smm<<<gs, 256, 0, stream>>>(T2, W, T3);
        dim3 gv(2, 4);
        k_vec<<<gv, 256, 0, stream>>>(b, W, r1);
        k_vec<<<gv, 256, 0, stream>>>(r1, W, r2);
    }

    k_out<<<(NG * 300 + 255) / 256, 256, 0, stream>>>(T3, su1, su2, gstart, r1, r2, b, (float*)d_out);
}